// Round 8
// baseline (1836.943 us; speedup 1.0000x reference)
//
#include <hip/hip_runtime.h>

// Problem constants (from reference)
constexpr int BATCH = 16384;
constexpr int NN    = 4096;    // NUM_NEURONS
constexpr int BS    = 32;      // BLOCK_SIZE
constexpr int NB    = NN / BS; // 128 blocks

constexpr int THREADS     = 256;   // 4 waves
constexpr int NBLK_PER_WG = 2;     // 64 cols, 256-B burst per row
constexpr int COLS        = BS * NBLK_PER_WG;        // 64
constexpr int ROWS_PER_WG = 512;
constexpr int ROWS_PER_IT = 64;    // 4 waves x 16 rows
constexpr int ITERS       = ROWS_PER_WG / ROWS_PER_IT; // 8
constexpr int COLGROUPS   = NB / NBLK_PER_WG;        // 64
constexpr int ROWTILES    = BATCH / ROWS_PER_WG;     // 32

typedef float f32x4 __attribute__((ext_vector_type(4)));
typedef float f32x2 __attribute__((ext_vector_type(2)));

// Lane layout: r = lane>>2 (16 rows/wave), q = lane&3. Lane owns 16 output
// cols {16j+4q..16j+4q+3 : j=0..3} of its row and holds matching v in w[j].
// v[row,k] broadcast: owner is lane (k>>2)&3 within the quad -> quad_perm DPP
// (VALU pipe). Per k-step: 4 conflict-free broadcast ds_read_b128 + 16 FMA.

template <int S>
__device__ __forceinline__ float qbcast(float x) {
    return __int_as_float(__builtin_amdgcn_update_dpp(
        0, __float_as_int(x), S * 0x55, 0xF, 0xF, true));
}

template <int K>
struct KStep {
    static __device__ __forceinline__ void run(const f32x4* __restrict__ w,
                                               const float* __restrict__ Alds,
                                               int q, float* __restrict__ acc) {
        constexpr int s = (K >> 2) & 3;  // owner lane within quad
        constexpr int h = K >> 4;        // which half of the 32-wide block
        constexpr int e = K & 3;         // component
        const float vk0 = qbcast<s>(w[h][e]);      // v for nblk0 (k=K)
        const float vk1 = qbcast<s>(w[2 + h][e]);  // v for nblk1 (k=K)
        const f32x4 a0 = *reinterpret_cast<const f32x4*>(Alds + K * BS + q * 4);
        const f32x4 a1 = *reinterpret_cast<const f32x4*>(Alds + K * BS + q * 4 + 16);
        const f32x4 a2 = *reinterpret_cast<const f32x4*>(Alds + 1024 + K * BS + q * 4);
        const f32x4 a3 = *reinterpret_cast<const f32x4*>(Alds + 1024 + K * BS + q * 4 + 16);
#pragma unroll
        for (int t = 0; t < 4; ++t) {
            acc[0  + t] = fmaf(vk0, a0[t], acc[0  + t]);
            acc[4  + t] = fmaf(vk0, a1[t], acc[4  + t]);
            acc[8  + t] = fmaf(vk1, a2[t], acc[8  + t]);
            acc[12 + t] = fmaf(vk1, a3[t], acc[12 + t]);
        }
        KStep<K + 1>::run(w, Alds, q, acc);
    }
};
template <>
struct KStep<BS> {
    static __device__ __forceinline__ void run(const f32x4* __restrict__,
                                               const float* __restrict__,
                                               int, float* __restrict__) {}
};

__global__ void tn_kernel(
    const float* __restrict__ v,
    const float* __restrict__ dx,
    const float* __restrict__ A,
    const float* __restrict__ Bm,
    const float* __restrict__ bsc,
    float* __restrict__ out)
{
    __shared__ float Alds[NBLK_PER_WG * BS * BS]; // 2 x A[k][l] (8 KB)
    __shared__ float Blds[COLS * 2];              // B rows for 64 cols (512 B)

    const int tid = threadIdx.x;
    const int cg  = blockIdx.x & (COLGROUPS - 1); // column group (2 nblks)
    const int rt  = blockIdx.x >> 6;              // row tile
    const int nb0 = cg * NBLK_PER_WG;

    // Stage A (8 KB): 256 threads x two f32x4
    {
        const f32x4* src = reinterpret_cast<const f32x4*>(A + nb0 * (BS * BS));
        reinterpret_cast<f32x4*>(Alds)[tid]       = src[tid];
        reinterpret_cast<f32x4*>(Alds)[tid + 256] = src[tid + 256];
        if (tid < COLS * 2 / 4)
            reinterpret_cast<f32x4*>(Blds)[tid] =
                reinterpret_cast<const f32x4*>(Bm + nb0 * (BS * 2))[tid];
    }
    __syncthreads();

    const float bias = *bsc;
    const int lane = tid & 63;
    const int wv   = tid >> 6;
    const int r    = lane >> 2;
    const int q    = lane & 3;

    const int row0 = rt * ROWS_PER_WG + wv * 16 + r;
    const size_t rb0 = (size_t)row0 * NN + nb0 * BS;
    constexpr size_t IT_STRIDE = (size_t)ROWS_PER_IT * NN;

    // 2-deep software pipeline, named registers, static rotation.
    f32x4 wA[4], wB[4], wC[4];
    f32x2 dA, dB, dC;

#pragma unroll
    for (int j = 0; j < 4; ++j) {
        wA[j] = *reinterpret_cast<const f32x4*>(v + rb0 + j * 16 + q * 4);
        wB[j] = *reinterpret_cast<const f32x4*>(v + rb0 + IT_STRIDE + j * 16 + q * 4);
    }
    dA = *reinterpret_cast<const f32x2*>(dx + (size_t)row0 * 2);
    dB = *reinterpret_cast<const f32x2*>(dx + (size_t)(row0 + ROWS_PER_IT) * 2);

#pragma unroll 1
    for (int it = 0; it < ITERS; ++it) {
        if (it < ITERS - 2) {
            const size_t rbn = rb0 + (size_t)(it + 2) * IT_STRIDE;
#pragma unroll
            for (int j = 0; j < 4; ++j)
                wC[j] = *reinterpret_cast<const f32x4*>(v + rbn + j * 16 + q * 4);
            dC = *reinterpret_cast<const f32x2*>(
                     dx + (size_t)(row0 + (it + 2) * ROWS_PER_IT) * 2);
        } else {
#pragma unroll
            for (int j = 0; j < 4; ++j) wC[j] = wA[j];
            dC = dA;
        }

        float acc[16] = {};
        KStep<0>::run(wA, Alds, q, acc);

        const size_t rbw = rb0 + (size_t)it * IT_STRIDE;
#pragma unroll
        for (int j = 0; j < 4; ++j) {
            // B entries for cols 16j+4q..16j+4q+3 from LDS (broadcast reads)
            const f32x4 Ba = *reinterpret_cast<const f32x4*>(Blds + (16 * j + 4 * q) * 2);
            const f32x4 Bb = *reinterpret_cast<const f32x4*>(Blds + (16 * j + 4 * q) * 2 + 4);
            f32x4 o;
            o.x = fmaxf(fmaf(dA.x, Ba.x, fmaf(dA.y, Ba.y, acc[4 * j + 0] + bias)), 0.f);
            o.y = fmaxf(fmaf(dA.x, Ba.z, fmaf(dA.y, Ba.w, acc[4 * j + 1] + bias)), 0.f);
            o.z = fmaxf(fmaf(dA.x, Bb.x, fmaf(dA.y, Bb.y, acc[4 * j + 2] + bias)), 0.f);
            o.w = fmaxf(fmaf(dA.x, Bb.z, fmaf(dA.y, Bb.w, acc[4 * j + 3] + bias)), 0.f);
            __builtin_nontemporal_store(
                o, reinterpret_cast<f32x4*>(out + rbw + j * 16 + q * 4));
        }

        // rotate pipeline (static, named)
#pragma unroll
        for (int j = 0; j < 4; ++j) { wA[j] = wB[j]; wB[j] = wC[j]; }
        dA = dB; dB = dC;
    }
}

extern "C" void kernel_launch(void* const* d_in, const int* in_sizes, int n_in,
                              void* d_out, int out_size, void* d_ws, size_t ws_size,
                              hipStream_t stream) {
    const float* v  = (const float*)d_in[0];  // [16384,4096]
    const float* dx = (const float*)d_in[1];  // [16384,2]
    const float* A  = (const float*)d_in[2];  // [128,32,32]
    const float* Bm = (const float*)d_in[3];  // [4096,2]
    const float* b  = (const float*)d_in[4];  // scalar
    float* out = (float*)d_out;               // [16384,4096]

    const int grid = COLGROUPS * ROWTILES; // 64 * 32 = 2048
    tn_kernel<<<dim3(grid), dim3(THREADS), 0, stream>>>(v, dx, A, Bm, b, out);
}

// Round 9
// 430.867 us; speedup vs baseline: 4.2634x; 4.2634x over previous
//
#include <hip/hip_runtime.h>

// Problem constants (from reference)
constexpr int BATCH = 16384;
constexpr int NN    = 4096;    // NUM_NEURONS
constexpr int BS    = 32;      // BLOCK_SIZE
constexpr int NB    = NN / BS; // 128 blocks

constexpr int THREADS     = 256;   // 4 waves
constexpr int NBLK_PER_WG = 2;     // 64 cols, 256-B burst per row
constexpr int COLS        = BS * NBLK_PER_WG;        // 64
constexpr int ROWS_PER_WG = 512;
constexpr int ROWS_PER_IT = 64;    // 4 waves x 16 rows
constexpr int ITERS       = ROWS_PER_WG / ROWS_PER_IT; // 8
constexpr int COLGROUPS   = NB / NBLK_PER_WG;        // 64
constexpr int ROWTILES    = BATCH / ROWS_PER_WG;     // 32

typedef float f32x4 __attribute__((ext_vector_type(4)));
typedef float f32x2 __attribute__((ext_vector_type(2)));

// Lane layout: r = lane>>2 (16 rows/wave), q = lane&3. Lane owns 16 output
// cols {16j+4q..16j+4q+3 : j=0..3} of its row and holds matching v in w[j].
// v[row,k] broadcast: owner is lane (k>>2)&3 within the quad -> quad_perm DPP
// (VALU pipe). Per k-step: 4 conflict-free broadcast ds_read_b128 + 16 FMA.
//
// NOTE (hard-won): ALWAYS declare __launch_bounds__(THREADS) with no
// min-waves arg. Without it hipcc assumes 1024-thread workgroups -> 64-VGPR
// cap -> spill (R8: 1837us). With a min-waves arg it squeezes -> spill
// (R5: 32 VGPR, R7: 64 VGPR). Let VGPR float under the 256-thread bound.

template <int S>
__device__ __forceinline__ float qbcast(float x) {
    return __int_as_float(__builtin_amdgcn_update_dpp(
        0, __float_as_int(x), S * 0x55, 0xF, 0xF, true));
}

template <int K>
struct KStep {
    static __device__ __forceinline__ void run(const f32x4* __restrict__ w,
                                               const float* __restrict__ Alds,
                                               int q, float* __restrict__ acc) {
        constexpr int s = (K >> 2) & 3;  // owner lane within quad
        constexpr int h = K >> 4;        // which half of the 32-wide block
        constexpr int e = K & 3;         // component
        const float vk0 = qbcast<s>(w[h][e]);      // v for nblk0 (k=K)
        const float vk1 = qbcast<s>(w[2 + h][e]);  // v for nblk1 (k=K)
        const f32x4 a0 = *reinterpret_cast<const f32x4*>(Alds + K * BS + q * 4);
        const f32x4 a1 = *reinterpret_cast<const f32x4*>(Alds + K * BS + q * 4 + 16);
        const f32x4 a2 = *reinterpret_cast<const f32x4*>(Alds + 1024 + K * BS + q * 4);
        const f32x4 a3 = *reinterpret_cast<const f32x4*>(Alds + 1024 + K * BS + q * 4 + 16);
#pragma unroll
        for (int t = 0; t < 4; ++t) {
            acc[0  + t] = fmaf(vk0, a0[t], acc[0  + t]);
            acc[4  + t] = fmaf(vk0, a1[t], acc[4  + t]);
            acc[8  + t] = fmaf(vk1, a2[t], acc[8  + t]);
            acc[12 + t] = fmaf(vk1, a3[t], acc[12 + t]);
        }
        KStep<K + 1>::run(w, Alds, q, acc);
    }
};
template <>
struct KStep<BS> {
    static __device__ __forceinline__ void run(const f32x4* __restrict__,
                                               const float* __restrict__,
                                               int, float* __restrict__) {}
};

__global__ __launch_bounds__(THREADS) void tn_kernel(
    const float* __restrict__ v,
    const float* __restrict__ dx,
    const float* __restrict__ A,
    const float* __restrict__ Bm,
    const float* __restrict__ bsc,
    float* __restrict__ out)
{
    __shared__ float Alds[NBLK_PER_WG * BS * BS]; // 2 x A[k][l] (8 KB)
    __shared__ float Blds[COLS * 2];              // B rows for 64 cols (512 B)

    const int tid = threadIdx.x;
    const int cg  = blockIdx.x & (COLGROUPS - 1); // column group (2 nblks)
    const int rt  = blockIdx.x >> 6;              // row tile
    const int nb0 = cg * NBLK_PER_WG;

    // Stage A (8 KB): 256 threads x two f32x4
    {
        const f32x4* src = reinterpret_cast<const f32x4*>(A + nb0 * (BS * BS));
        reinterpret_cast<f32x4*>(Alds)[tid]       = src[tid];
        reinterpret_cast<f32x4*>(Alds)[tid + 256] = src[tid + 256];
        if (tid < COLS * 2 / 4)
            reinterpret_cast<f32x4*>(Blds)[tid] =
                reinterpret_cast<const f32x4*>(Bm + nb0 * (BS * 2))[tid];
    }
    __syncthreads();

    const float bias = *bsc;
    const int lane = tid & 63;
    const int wv   = tid >> 6;
    const int r    = lane >> 2;
    const int q    = lane & 3;

    const int row0 = rt * ROWS_PER_WG + wv * 16 + r;
    const size_t rb0 = (size_t)row0 * NN + nb0 * BS;
    constexpr size_t IT_STRIDE = (size_t)ROWS_PER_IT * NN;

    // 2-deep software pipeline, named registers, static rotation.
    f32x4 wA[4], wB[4], wC[4];
    f32x2 dA, dB, dC;

#pragma unroll
    for (int j = 0; j < 4; ++j) {
        wA[j] = *reinterpret_cast<const f32x4*>(v + rb0 + j * 16 + q * 4);
        wB[j] = *reinterpret_cast<const f32x4*>(v + rb0 + IT_STRIDE + j * 16 + q * 4);
    }
    dA = *reinterpret_cast<const f32x2*>(dx + (size_t)row0 * 2);
    dB = *reinterpret_cast<const f32x2*>(dx + (size_t)(row0 + ROWS_PER_IT) * 2);

#pragma unroll 1
    for (int it = 0; it < ITERS; ++it) {
        if (it < ITERS - 2) {
            const size_t rbn = rb0 + (size_t)(it + 2) * IT_STRIDE;
#pragma unroll
            for (int j = 0; j < 4; ++j)
                wC[j] = *reinterpret_cast<const f32x4*>(v + rbn + j * 16 + q * 4);
            dC = *reinterpret_cast<const f32x2*>(
                     dx + (size_t)(row0 + (it + 2) * ROWS_PER_IT) * 2);
        } else {
#pragma unroll
            for (int j = 0; j < 4; ++j) wC[j] = wA[j];
            dC = dA;
        }

        float acc[16] = {};
        KStep<0>::run(wA, Alds, q, acc);

        const size_t rbw = rb0 + (size_t)it * IT_STRIDE;
#pragma unroll
        for (int j = 0; j < 4; ++j) {
            // B entries for cols 16j+4q..16j+4q+3 from LDS (broadcast reads)
            const f32x4 Ba = *reinterpret_cast<const f32x4*>(Blds + (16 * j + 4 * q) * 2);
            const f32x4 Bb = *reinterpret_cast<const f32x4*>(Blds + (16 * j + 4 * q) * 2 + 4);
            f32x4 o;
            o.x = fmaxf(fmaf(dA.x, Ba.x, fmaf(dA.y, Ba.y, acc[4 * j + 0] + bias)), 0.f);
            o.y = fmaxf(fmaf(dA.x, Ba.z, fmaf(dA.y, Ba.w, acc[4 * j + 1] + bias)), 0.f);
            o.z = fmaxf(fmaf(dA.x, Bb.x, fmaf(dA.y, Bb.y, acc[4 * j + 2] + bias)), 0.f);
            o.w = fmaxf(fmaf(dA.x, Bb.z, fmaf(dA.y, Bb.w, acc[4 * j + 3] + bias)), 0.f);
            __builtin_nontemporal_store(
                o, reinterpret_cast<f32x4*>(out + rbw + j * 16 + q * 4));
        }

        // rotate pipeline (static, named)
#pragma unroll
        for (int j = 0; j < 4; ++j) { wA[j] = wB[j]; wB[j] = wC[j]; }
        dA = dB; dB = dC;
    }
}

extern "C" void kernel_launch(void* const* d_in, const int* in_sizes, int n_in,
                              void* d_out, int out_size, void* d_ws, size_t ws_size,
                              hipStream_t stream) {
    const float* v  = (const float*)d_in[0];  // [16384,4096]
    const float* dx = (const float*)d_in[1];  // [16384,2]
    const float* A  = (const float*)d_in[2];  // [128,32,32]
    const float* Bm = (const float*)d_in[3];  // [4096,2]
    const float* b  = (const float*)d_in[4];  // scalar
    float* out = (float*)d_out;               // [16384,4096]

    const int grid = COLGROUPS * ROWTILES; // 64 * 32 = 2048
    tn_kernel<<<dim3(grid), dim3(THREADS), 0, stream>>>(v, dx, A, Bm, b, out);
}

// Round 10
// 112.291 us; speedup vs baseline: 16.3588x; 3.8371x over previous
//
#include <hip/hip_runtime.h>

// Problem constants (from reference)
constexpr int BATCH = 16384;
constexpr int NN    = 4096;    // NUM_NEURONS
constexpr int BS    = 32;      // BLOCK_SIZE
constexpr int NB    = NN / BS; // 128 blocks

constexpr int THREADS     = 256;   // 4 waves
constexpr int NBLK        = 2;     // blocks per WG -> 256-B contiguous span/row
constexpr int COLS        = BS * NBLK;               // 64
constexpr int ROWS_PER_WG = 512;
constexpr int ROWS_PER_IT = 64;    // 4 waves x 16 rows
constexpr int ITERS       = ROWS_PER_WG / ROWS_PER_IT; // 8
constexpr int COLGROUPS   = NB / NBLK;               // 64
constexpr int ROWTILES    = BATCH / ROWS_PER_WG;     // 32

typedef float f32x4 __attribute__((ext_vector_type(4)));
typedef float f32x2 __attribute__((ext_vector_type(2)));

// Lane layout: r = lane>>2 (16 rows/wave), q = lane&3.
// w[j] = v[row, 16j+4q .. 16j+4q+3], j=0..3  (256 B of the row, quad-dense).
// Block b (0,1), k kk (0..31): v-col 32b+kk = w[2b+(kk>>4)][kk&3] of quad-lane
// (kk>>2)&3 -> quad_perm DPP broadcast (VALU pipe, zero DS traffic).
// A-reads: 2 ds_read_b128 per (b,kk), addresses depend only on q -> 4 distinct
// 16-B addrs, 16-way broadcast, ~1 bank round (conflict-free).
//
// NOTE (hard-won): ALWAYS declare __launch_bounds__(THREADS) with no
// min-waves arg (R8: default 1024-thr assumption -> 64-VGPR cap -> spill;
// R5/R7: forced min-waves -> squeeze -> spill). And bound LDS-read hoisting
// explicitly (R9: full unroll w/o fences -> 256 VGPR -> 1 wave/SIMD, 431us):
// sched_barrier(0) every 4 k-steps caps the live ds_read window.

template <int S>
__device__ __forceinline__ float qbcast(float x) {
    return __int_as_float(__builtin_amdgcn_update_dpp(
        0, __float_as_int(x), S * 0x55, 0xF, 0xF, true));
}

template <int KK>
struct KStep {
    static __device__ __forceinline__ void run(const f32x4* __restrict__ w,
                                               const float* __restrict__ Alds,
                                               int q,
                                               float* __restrict__ acc0,
                                               float* __restrict__ acc1) {
        constexpr int b  = KK >> 5;          // block within WG
        constexpr int kk = KK & 31;          // k within block
        constexpr int j  = 2 * b + (kk >> 4);
        constexpr int e  = kk & 3;
        constexpr int s  = (kk >> 2) & 3;    // source lane within quad
        const float vk = qbcast<s>(w[j][e]);
        const float* Ab = Alds + (b * 32 + kk) * 32;
        const f32x4 a0 = *reinterpret_cast<const f32x4*>(Ab + q * 4);
        const f32x4 a1 = *reinterpret_cast<const f32x4*>(Ab + q * 4 + 16);
        float* __restrict__ acc = b ? acc1 : acc0;
#pragma unroll
        for (int t = 0; t < 4; ++t) {
            acc[t]     = fmaf(vk, a0[t], acc[t]);
            acc[4 + t] = fmaf(vk, a1[t], acc[4 + t]);
        }
        if constexpr ((KK & 3) == 3) __builtin_amdgcn_sched_barrier(0);
        KStep<KK + 1>::run(w, Alds, q, acc0, acc1);
    }
};
template <>
struct KStep<2 * BS> {
    static __device__ __forceinline__ void run(const f32x4* __restrict__,
                                               const float* __restrict__, int,
                                               float* __restrict__,
                                               float* __restrict__) {}
};

__global__ __launch_bounds__(THREADS) void tn_kernel(
    const float* __restrict__ v,
    const float* __restrict__ dx,
    const float* __restrict__ A,
    const float* __restrict__ Bm,
    const float* __restrict__ bsc,
    float* __restrict__ out)
{
    __shared__ float Alds[NBLK * BS * BS]; // [b][kk][col] (8 KB)
    __shared__ float Blds[COLS * 2];       // B rows for 64 cols (512 B)

    const int tid = threadIdx.x;
    const int cg  = blockIdx.x & (COLGROUPS - 1);
    const int rt  = blockIdx.x >> 6;
    const int nb0 = cg * NBLK;

    // Stage A (8 KB = 512 f32x4): 256 threads x 2; B: 32 f32x4.
    {
        const f32x4* src = reinterpret_cast<const f32x4*>(A + nb0 * (BS * BS));
        reinterpret_cast<f32x4*>(Alds)[tid]       = src[tid];
        reinterpret_cast<f32x4*>(Alds)[tid + 256] = src[tid + 256];
        if (tid < COLS * 2 / 4)
            reinterpret_cast<f32x4*>(Blds)[tid] =
                reinterpret_cast<const f32x4*>(Bm + nb0 * (BS * 2))[tid];
    }
    __syncthreads();

    const float bias = *bsc;
    const int lane = tid & 63;
    const int wv   = tid >> 6;
    const int r    = lane >> 2;
    const int q    = lane & 3;

    const int row0 = rt * ROWS_PER_WG + wv * 16 + r;
    const size_t rb0 = (size_t)row0 * NN + nb0 * BS;
    constexpr size_t IT_STRIDE = (size_t)ROWS_PER_IT * NN;

    // 1-deep prefetch (R6-proven), named registers.
    f32x4 w[4], wn[4];
    f32x2 dd, ddn;
#pragma unroll
    for (int j = 0; j < 4; ++j)
        w[j] = *reinterpret_cast<const f32x4*>(v + rb0 + j * 16 + q * 4);
    dd = *reinterpret_cast<const f32x2*>(dx + (size_t)row0 * 2);

#pragma unroll 1
    for (int it = 0; it < ITERS; ++it) {
        if (it < ITERS - 1) {
            const size_t rbn = rb0 + (size_t)(it + 1) * IT_STRIDE;
#pragma unroll
            for (int j = 0; j < 4; ++j)
                wn[j] = *reinterpret_cast<const f32x4*>(v + rbn + j * 16 + q * 4);
            ddn = *reinterpret_cast<const f32x2*>(
                      dx + (size_t)(row0 + (it + 1) * ROWS_PER_IT) * 2);
        } else {
#pragma unroll
            for (int j = 0; j < 4; ++j) wn[j] = w[j];
            ddn = dd;
        }

        float acc0[8] = {}, acc1[8] = {};
        KStep<0>::run(w, Alds, q, acc0, acc1);

        const size_t rbw = rb0 + (size_t)it * IT_STRIDE;
#pragma unroll
        for (int b = 0; b < NBLK; ++b) {
            const float* __restrict__ acc = b ? acc1 : acc0;
#pragma unroll
            for (int h = 0; h < 2; ++h) {
                const int c0 = 32 * b + 16 * h + 4 * q;   // first of 4 cols
                const f32x4 Ba = *reinterpret_cast<const f32x4*>(Blds + c0 * 2);
                const f32x4 Bb = *reinterpret_cast<const f32x4*>(Blds + c0 * 2 + 4);
                f32x4 o;
                o.x = fmaxf(fmaf(dd.x, Ba.x, fmaf(dd.y, Ba.y, acc[4 * h + 0] + bias)), 0.f);
                o.y = fmaxf(fmaf(dd.x, Ba.z, fmaf(dd.y, Ba.w, acc[4 * h + 1] + bias)), 0.f);
                o.z = fmaxf(fmaf(dd.x, Bb.x, fmaf(dd.y, Bb.y, acc[4 * h + 2] + bias)), 0.f);
                o.w = fmaxf(fmaf(dd.x, Bb.z, fmaf(dd.y, Bb.w, acc[4 * h + 3] + bias)), 0.f);
                __builtin_nontemporal_store(
                    o, reinterpret_cast<f32x4*>(out + rbw + 32 * b + 16 * h + q * 4));
            }
        }

#pragma unroll
        for (int j = 0; j < 4; ++j) w[j] = wn[j];
        dd = ddn;
    }
}

extern "C" void kernel_launch(void* const* d_in, const int* in_sizes, int n_in,
                              void* d_out, int out_size, void* d_ws, size_t ws_size,
                              hipStream_t stream) {
    const float* v  = (const float*)d_in[0];  // [16384,4096]
    const float* dx = (const float*)d_in[1];  // [16384,2]
    const float* A  = (const float*)d_in[2];  // [128,32,32]
    const float* Bm = (const float*)d_in[3];  // [4096,2]
    const float* b  = (const float*)d_in[4];  // scalar
    float* out = (float*)d_out;               // [16384,4096]

    const int grid = COLGROUPS * ROWTILES; // 64 * 32 = 2048
    tn_kernel<<<dim3(grid), dim3(THREADS), 0, stream>>>(v, dx, A, Bm, b, out);
}